// Round 4
// baseline (170.993 us; speedup 1.0000x reference)
//
#include <hip/hip_runtime.h>
#include <math.h>

#define B_ 2
#define T_ 1024
#define E_ 1024
#define H_ 16
#define D_ 64
#define M_ (B_*T_)

typedef __bf16 bf16x8 __attribute__((ext_vector_type(8)));
typedef __bf16 bf16x4 __attribute__((ext_vector_type(4)));
typedef float f32x4 __attribute__((ext_vector_type(4)));

// swizzled LDS addressing for attn tiles: row-major [64 rows][128 bytes], byte ^= (row&7)<<4
__device__ __forceinline__ void* ldsp(__bf16* base, int row, int byte) {
  return (char*)base + row * 128 + (byte ^ ((row & 7) << 4));
}

__device__ __forceinline__ void gload_lds16(const void* g, void* l) {
  __builtin_amdgcn_global_load_lds((const __attribute__((address_space(1))) void*)g,
                                   (__attribute__((address_space(3))) void*)l, 16, 0, 0);
}

// ---------------- K-1: f32 -> bf16 conversions (x, Wqkv, Wout) ----------------
#define XV4 524288     // (2*1024*1024)/4
#define WQV4 786432    // (3072*1024)/4
#define WOV4 262144    // (1024*1024)/4
#define TOTV4 (XV4 + WQV4 + WOV4)
__global__ __launch_bounds__(256) void conv_kernel(
    const float* __restrict__ x, const float* __restrict__ Wqkv,
    const float* __restrict__ Wout,
    __bf16* __restrict__ xb, __bf16* __restrict__ Wqkvb, __bf16* __restrict__ Woutb) {
  for (size_t i = (size_t)blockIdx.x * blockDim.x + threadIdx.x; i < TOTV4;
       i += (size_t)gridDim.x * blockDim.x) {
    const float4* src; __bf16* dst; size_t off;
    if (i < XV4)            { src = (const float4*)x;    dst = xb;    off = i; }
    else if (i < XV4+WQV4)  { src = (const float4*)Wqkv; dst = Wqkvb; off = i - XV4; }
    else                    { src = (const float4*)Wout; dst = Woutb; off = i - XV4 - WQV4; }
    float4 val = src[off];
    bf16x4 o = {(__bf16)val.x, (__bf16)val.y, (__bf16)val.z, (__bf16)val.w};
    *(bf16x4*)(dst + off * 4) = o;
  }
}

// ---------------- K0: importance (spike) + alpha (f32 — sign decision!) ----------------
__global__ __launch_bounds__(256) void imp_alpha_kernel(
    const float* __restrict__ x,
    const float* __restrict__ Wimp, const float* __restrict__ bimp,
    const float* __restrict__ Walpha, const float* __restrict__ balpha,
    const float* __restrict__ thr_p,
    float* __restrict__ spike, float* __restrict__ alpha) {
  int m = blockIdx.x;
  int tid = threadIdx.x;
  const float* xr = x + (size_t)m * E_;
  float part[17];
#pragma unroll
  for (int i = 0; i < 17; ++i) part[i] = 0.f;
  for (int e = tid; e < E_; e += 256) {
    float xv = xr[e];
    part[16] += xv * Wimp[e];
#pragma unroll
    for (int h = 0; h < 16; ++h) part[h] += xv * Walpha[h * E_ + e];
  }
  __shared__ float red[17][4];
  int lane = tid & 63, wv = tid >> 6;
#pragma unroll
  for (int i = 0; i < 17; ++i) {
    float v = part[i];
    for (int off = 32; off > 0; off >>= 1) v += __shfl_down(v, off, 64);
    if (lane == 0) red[i][wv] = v;
  }
  __syncthreads();
  if (tid < 17) {
    float v = red[tid][0] + red[tid][1] + red[tid][2] + red[tid][3];
    if (tid == 16) {
      float z = v + bimp[0];
      float sig = 1.f / (1.f + expf(-z));
      spike[m] = (sig > thr_p[0]) ? 1.f : 0.f;
    } else {
      float z = v + balpha[tid];
      float a = 1.f / (1.f + expf(-z));
      int b = m >> 10, t = m & (T_ - 1);
      alpha[((size_t)(b * H_ + tid)) * T_ + t] = a;
    }
  }
}

// ---------------- K1: QKV GEMM — bf16 MFMA, 128x128 tile ----------------
__global__ __launch_bounds__(256) void qkv_gemm_kernel(
    const __bf16* __restrict__ A, const __bf16* __restrict__ Bm,
    const float* __restrict__ bias,
    __bf16* __restrict__ q, __bf16* __restrict__ k, __bf16* __restrict__ v) {
  __shared__ __bf16 As[128 * 32];
  __shared__ __bf16 Bs[128 * 32];
  const int K = E_;
  int tid = threadIdx.x;
  int w = tid >> 6, lane = tid & 63, lr = lane & 15, g = lane >> 4;
  int m0 = blockIdx.y * 128, n0 = blockIdx.x * 128;
  int wr = (w >> 1) * 64, wc = (w & 1) * 64;

  int task0 = tid, task1 = tid + 256;
  int r0s = task0 >> 2, c0s = task0 & 3;
  int r1s = task1 >> 2, c1s = task1 & 3;
  const __bf16* gA0 = A + (size_t)(m0 + r0s) * K + c0s * 8;
  const __bf16* gA1 = A + (size_t)(m0 + r1s) * K + c1s * 8;
  const __bf16* gB0 = Bm + (size_t)(n0 + r0s) * K + c0s * 8;
  const __bf16* gB1 = Bm + (size_t)(n0 + r1s) * K + c1s * 8;
  __bf16* lA0 = As + task0 * 8;
  __bf16* lA1 = As + task1 * 8;
  __bf16* lB0 = Bs + task0 * 8;
  __bf16* lB1 = Bs + task1 * 8;

  f32x4 acc[4][4];
#pragma unroll
  for (int i = 0; i < 4; ++i)
#pragma unroll
    for (int j = 0; j < 4; ++j) acc[i][j] = (f32x4){0.f, 0.f, 0.f, 0.f};

  for (int k0 = 0; k0 < K; k0 += 32) {
    gload_lds16(gA0, lA0); gload_lds16(gA1, lA1);
    gload_lds16(gB0, lB0); gload_lds16(gB1, lB1);
    gA0 += 32; gA1 += 32; gB0 += 32; gB1 += 32;
    __syncthreads();
    bf16x8 af[4], bf[4];
#pragma unroll
    for (int i = 0; i < 4; ++i) af[i] = *(bf16x8*)&As[(wr + i * 16 + lr) * 32 + g * 8];
#pragma unroll
    for (int j = 0; j < 4; ++j) bf[j] = *(bf16x8*)&Bs[(wc + j * 16 + lr) * 32 + g * 8];
#pragma unroll
    for (int i = 0; i < 4; ++i)
#pragma unroll
      for (int j = 0; j < 4; ++j)
        acc[i][j] = __builtin_amdgcn_mfma_f32_16x16x32_bf16(af[i], bf[j], acc[i][j], 0, 0, 0);
    __syncthreads();
  }

#pragma unroll
  for (int i = 0; i < 4; ++i) {
#pragma unroll
    for (int r = 0; r < 4; ++r) {
      int m = m0 + wr + i * 16 + g * 4 + r;
      int b = m >> 10, t = m & (T_ - 1);
#pragma unroll
      for (int j = 0; j < 4; ++j) {
        int n = n0 + wc + j * 16 + lr;
        float val = acc[i][j][r] + bias[n];
        int comp = n >> 10, h = (n >> 6) & 15, d = n & 63;
        __bf16* dst = (comp == 0) ? q : ((comp == 1) ? k : v);
        dst[(((size_t)(b * H_ + h)) * T_ + t) * 64 + d] = (__bf16)val;
      }
    }
  }
}

// ---------------- K2: hyperboloid map (bf16 in/out, f32 math) ----------------
__global__ __launch_bounds__(256) void hyp_kernel(
    const __bf16* __restrict__ q, const __bf16* __restrict__ k,
    const float* __restrict__ qk_scale_p,
    __bf16* __restrict__ qh, __bf16* __restrict__ khn) {
  int wid = blockIdx.x * 4 + (threadIdx.x >> 6);
  int lane = threadIdx.x & 63;
  int is_k = wid >> 15;
  int row = wid & 32767;
  const __bf16* src = (is_k ? k : q) + (size_t)row * 64;
  float u = (float)src[lane];
  float nsq = u * u;
#pragma unroll
  for (int off = 32; off > 0; off >>= 1) nsq += __shfl_xor(nsq, off, 64);
  float norm = fmaxf(sqrtf(nsq), 1e-12f);
  float ss = 1.5f / (1.f + expf(-qk_scale_p[0]));
  float un = u / norm * ss;
  float s2 = un * un;
  float tot = s2;
#pragma unroll
  for (int off = 32; off > 0; off >>= 1) tot += __shfl_xor(tot, off, 64);
  float un0 = __shfl(un, 0, 64);
  float mink = tot - 2.f * un0 * un0;
  float nomin = sqrtf(fmaxf(mink, 1e-8f));
  float sc = sinhf(nomin) / nomin;
  float r = sc * un;
  float sp2 = (lane == 0) ? 0.f : r * r;
  float sps = sp2;
#pragma unroll
  for (int off = 32; off > 0; off >>= 1) sps += __shfl_xor(sps, off, 64);
  float tm = sqrtf(1.f + sps);
  float outv = (lane == 0) ? tm : r;
  if (is_k && lane != 0) outv = -outv;  // fold Minkowski sign
  (is_k ? khn : qh)[(size_t)row * 64 + lane] = (__bf16)outv;
}

// ---------------- K3: MFMA dual-geometry flash attention ----------------
// balanced pairing: blocks (c, c+256) land on the same CU (round-robin model);
// qi mapping makes each pair's tile-work sum to 17.
__global__ __launch_bounds__(256) void attn_kernel(
    const __bf16* __restrict__ q, const __bf16* __restrict__ k, const __bf16* __restrict__ v,
    const __bf16* __restrict__ qh, const __bf16* __restrict__ khn,
    const float* __restrict__ alpha, const float* __restrict__ spike,
    const float* __restrict__ log_k, __bf16* __restrict__ y) {
  __shared__ __bf16 q_s[64 * 64];
  __shared__ __bf16 qh_s[64 * 64];
  __shared__ __bf16 k_s[64 * 64];
  __shared__ __bf16 kh_s[64 * 64];
  __shared__ __bf16 vt_s[64 * 64];
  __shared__ __bf16 p_s[64 * 64];

  int bid = blockIdx.x;
  int bq = bid >> 5;                       // 0..15
  int qi = (bq < 8) ? (15 - bq) : (bq - 8);  // pair sums: (16-u)+(u+1)=17 tiles
  int bh = bid & 31;
  int b = bh >> 4, h = bh & 15;
  int t0 = qi * 64;
  int tid = threadIdx.x;
  int w = tid >> 6, lane = tid & 63;
  int lr = lane & 15, g = lane >> 4;
  int trow = w * 16;
  const size_t base = (size_t)bh * T_ * 64;

  // staging task decomposition (row-major 16B chunks)
  int task0 = tid, task1 = tid + 256;
  int row0 = task0 >> 3, cj0 = task0 & 7;
  int row1 = task1 >> 3, cj1 = task1 & 7;
  int srow0 = task0 & 63, dc0 = task0 >> 6;
  int srow1 = task1 & 63, dc1 = task1 >> 6;

  // ---- stage Q, QH (swizzled) ----
  {
    bf16x8 a0 = *(const bf16x8*)(q + base + (size_t)(t0 + row0) * 64 + cj0 * 8);
    bf16x8 c0 = *(const bf16x8*)(qh + base + (size_t)(t0 + row0) * 64 + cj0 * 8);
    bf16x8 a1 = *(const bf16x8*)(q + base + (size_t)(t0 + row1) * 64 + cj1 * 8);
    bf16x8 c1 = *(const bf16x8*)(qh + base + (size_t)(t0 + row1) * 64 + cj1 * 8);
    *(bf16x8*)ldsp(q_s, row0, cj0 * 16) = a0;
    *(bf16x8*)ldsp(qh_s, row0, cj0 * 16) = c0;
    *(bf16x8*)ldsp(q_s, row1, cj1 * 16) = a1;
    *(bf16x8*)ldsp(qh_s, row1, cj1 * 16) = c1;
  }

  // constants (log2-domain softmax: fold log2e into both blend scales)
  float curv = log1pf(expf(log_k[h])) + 1e-6f;
  float hc = 0.69314718056f / curv;        // ln2 / curv  (dist in log2 units)
  const float ec = 0.18033688f;            // 0.125 * log2(e)
  int tg[4];
  float al[4], spv[4];
#pragma unroll
  for (int r = 0; r < 4; ++r) {
    tg[r] = t0 + trow + g * 4 + r;
    al[r] = alpha[(size_t)bh * T_ + tg[r]];
    spv[r] = spike[(size_t)b * T_ + tg[r]];
  }

  // ---- prefetch tile 0 into registers (T14 async-stage split) ----
  bf16x8 rk0, rk1, rkh0, rkh1, rv0, rv1;
  {
    rk0  = *(const bf16x8*)(k   + base + (size_t)(row0) * 64 + cj0 * 8);
    rkh0 = *(const bf16x8*)(khn + base + (size_t)(row0) * 64 + cj0 * 8);
    rk1  = *(const bf16x8*)(k   + base + (size_t)(row1) * 64 + cj1 * 8);
    rkh1 = *(const bf16x8*)(khn + base + (size_t)(row1) * 64 + cj1 * 8);
    rv0  = *(const bf16x8*)(v   + base + (size_t)(srow0) * 64 + dc0 * 8);
    rv1  = *(const bf16x8*)(v   + base + (size_t)(srow1) * 64 + dc1 * 8);
  }

  __syncthreads();
  bf16x8 aq0 = *(bf16x8*)ldsp(q_s, trow + lr, g * 16);
  bf16x8 aq1 = *(bf16x8*)ldsp(q_s, trow + lr, 64 + g * 16);
  bf16x8 ah0 = *(bf16x8*)ldsp(qh_s, trow + lr, g * 16);
  bf16x8 ah1 = *(bf16x8*)ldsp(qh_s, trow + lr, 64 + g * 16);

  float m_r[4] = {-1e30f, -1e30f, -1e30f, -1e30f};
  float l_r[4] = {0.f, 0.f, 0.f, 0.f};
  f32x4 acc[4];
#pragma unroll
  for (int n = 0; n < 4; ++n) acc[n] = (f32x4){0.f, 0.f, 0.f, 0.f};

  for (int st = 0; st <= qi; ++st) {
    int s0 = st * 64;
    bool diag = (st == qi);
    __syncthreads();
    // ---- write prefetched tile to LDS ----
    *(bf16x8*)ldsp(k_s, row0, cj0 * 16) = rk0;
    *(bf16x8*)ldsp(kh_s, row0, cj0 * 16) = rkh0;
    *(bf16x8*)ldsp(k_s, row1, cj1 * 16) = rk1;
    *(bf16x8*)ldsp(kh_s, row1, cj1 * 16) = rkh1;
#pragma unroll
    for (int i = 0; i < 8; ++i) {
      *(__bf16*)ldsp(vt_s, dc0 * 8 + i, srow0 * 2) = rv0[i];
      *(__bf16*)ldsp(vt_s, dc1 * 8 + i, srow1 * 2) = rv1[i];
    }
    // ---- issue next tile's global loads (overlap with compute) ----
    if (!diag) {
      int sn = s0 + 64;
      rk0  = *(const bf16x8*)(k   + base + (size_t)(sn + row0) * 64 + cj0 * 8);
      rkh0 = *(const bf16x8*)(khn + base + (size_t)(sn + row0) * 64 + cj0 * 8);
      rk1  = *(const bf16x8*)(k   + base + (size_t)(sn + row1) * 64 + cj1 * 8);
      rkh1 = *(const bf16x8*)(khn + base + (size_t)(sn + row1) * 64 + cj1 * 8);
      rv0  = *(const bf16x8*)(v   + base + (size_t)(sn + srow0) * 64 + dc0 * 8);
      rv1  = *(const bf16x8*)(v   + base + (size_t)(sn + srow1) * 64 + dc1 * 8);
    }
    __syncthreads();

    // ---- per-j: MFMA scores + blend (causal only on diagonal tile) ----
    float pv[4][4];
    float pmax[4] = {-1e30f, -1e30f, -1e30f, -1e30f};
#pragma unroll
    for (int j = 0; j < 4; ++j) {
      if (diag && (s0 + j * 16 > t0 + trow + 15)) {   // wave-uniform: fully masked
#pragma unroll
        for (int r = 0; r < 4; ++r) pv[j][r] = -1e30f;
        continue;
      }
      bf16x8 bk0 = *(bf16x8*)ldsp(k_s, j * 16 + lr, g * 16);
      bf16x8 bk1 = *(bf16x8*)ldsp(k_s, j * 16 + lr, 64 + g * 16);
      f32x4 z = {0.f, 0.f, 0.f, 0.f};
      z = __builtin_amdgcn_mfma_f32_16x16x32_bf16(aq0, bk0, z, 0, 0, 0);
      f32x4 se = __builtin_amdgcn_mfma_f32_16x16x32_bf16(aq1, bk1, z, 0, 0, 0);
      bf16x8 bh0 = *(bf16x8*)ldsp(kh_s, j * 16 + lr, g * 16);
      bf16x8 bh1 = *(bf16x8*)ldsp(kh_s, j * 16 + lr, 64 + g * 16);
      f32x4 z2 = {0.f, 0.f, 0.f, 0.f};
      z2 = __builtin_amdgcn_mfma_f32_16x16x32_bf16(ah0, bh0, z2, 0, 0, 0);
      f32x4 sh = __builtin_amdgcn_mfma_f32_16x16x32_bf16(ah1, bh1, z2, 0, 0, 0);
      int sg = s0 + j * 16 + lr;
#pragma unroll
      for (int r = 0; r < 4; ++r) {
        float sc_e = se[r] * ec;
        float md = fmaxf(sh[r], 1.0f + 1e-6f);
        float l2 = __log2f(md + sqrtf(fmaf(md, md, -1.f)));  // acosh in log2 units
        float t = fmaf(l2 * l2, hc, sc_e);
        float s = fmaf(-al[r], t, sc_e);                      // (1-a)e - a*h, log2 dom
        if (diag && sg > tg[r]) s = -1e30f;
        pv[j][r] = s;
        pmax[r] = fmaxf(pmax[r], s);
      }
    }
    // ---- online softmax (log2 domain) ----
#pragma unroll
    for (int r = 0; r < 4; ++r) {
      float mx = pmax[r];
      mx = fmaxf(mx, __shfl_xor(mx, 1, 64));
      mx = fmaxf(mx, __shfl_xor(mx, 2, 64));
      mx = fmaxf(mx, __shfl_xor(mx, 4, 64));
      mx = fmaxf(mx, __shfl_xor(mx, 8, 64));
      float mn = fmaxf(m_r[r], mx);
      float fac = exp2f(m_r[r] - mn);
      m_r[r] = mn;
      float ls = 0.f;
#pragma unroll
      for (int j = 0; j < 4; ++j) { pv[j][r] = exp2f(pv[j][r] - mn); ls += pv[j][r]; }
      ls += __shfl_xor(ls, 1, 64);
      ls += __shfl_xor(ls, 2, 64);
      ls += __shfl_xor(ls, 4, 64);
      ls += __shfl_xor(ls, 8, 64);
      l_r[r] = l_r[r] * fac + ls;
#pragma unroll
      for (int n = 0; n < 4; ++n) acc[n][r] *= fac;
    }
#pragma unroll
    for (int j = 0; j < 4; ++j)
#pragma unroll
      for (int r = 0; r < 4; ++r)
        *(__bf16*)ldsp(p_s, trow + g * 4 + r, (j * 16 + lr) * 2) = (__bf16)pv[j][r];
    __syncthreads();

    bf16x8 ap0 = *(bf16x8*)ldsp(p_s, trow + lr, g * 16);
    bf16x8 ap1 = *(bf16x8*)ldsp(p_s, trow + lr, 64 + g * 16);
#pragma unroll
    for (int n = 0; n < 4; ++n) {
      bf16x8 bv0 = *(bf16x8*)ldsp(vt_s, n * 16 + lr, g * 16);
      bf16x8 bv1 = *(bf16x8*)ldsp(vt_s, n * 16 + lr, 64 + g * 16);
      acc[n] = __builtin_amdgcn_mfma_f32_16x16x32_bf16(ap0, bv0, acc[n], 0, 0, 0);
      acc[n] = __builtin_amdgcn_mfma_f32_16x16x32_bf16(ap1, bv1, acc[n], 0, 0, 0);
    }
  }

#pragma unroll
  for (int r = 0; r < 4; ++r) {
    float iv = spv[r] / l_r[r];
#pragma unroll
    for (int n = 0; n < 4; ++n) {
      y[((size_t)(b * T_ + tg[r])) * E_ + h * 64 + n * 16 + lr] =
          (__bf16)(acc[n][r] * iv);
    }
  }
}

// ---------------- K4: output projection — bf16 MFMA, f32 out ----------------
__global__ __launch_bounds__(256) void out_gemm_kernel(
    const __bf16* __restrict__ A, const __bf16* __restrict__ Bm,
    const float* __restrict__ bias, float* __restrict__ outp) {
  __shared__ __bf16 As[128 * 32];
  __shared__ __bf16 Bs[128 * 32];
  const int K = E_;
  int tid = threadIdx.x;
  int w = tid >> 6, lane = tid & 63, lr = lane & 15, g = lane >> 4;
  int m0 = blockIdx.y * 128, n0 = blockIdx.x * 128;
  int wr = (w >> 1) * 64, wc = (w & 1) * 64;

  int task0 = tid, task1 = tid + 256;
  int r0s = task0 >> 2, c0s = task0 & 3;
  int r1s = task1 >> 2, c1s = task1 & 3;
  const __bf16* gA0 = A + (size_t)(m0 + r0s) * K + c0s * 8;
  const __bf16* gA1 = A + (size_t)(m0 + r1s) * K + c1s * 8;
  const __bf16* gB0 = Bm + (size_t)(n0 + r0s) * K + c0s * 8;
  const __bf16* gB1 = Bm + (size_t)(n0 + r1s) * K + c1s * 8;
  __bf16* lA0 = As + task0 * 8;
  __bf16* lA1 = As + task1 * 8;
  __bf16* lB0 = Bs + task0 * 8;
  __bf16* lB1 = Bs + task1 * 8;

  f32x4 acc[4][4];
#pragma unroll
  for (int i = 0; i < 4; ++i)
#pragma unroll
    for (int j = 0; j < 4; ++j) acc[i][j] = (f32x4){0.f, 0.f, 0.f, 0.f};

  for (int k0 = 0; k0 < K; k0 += 32) {
    gload_lds16(gA0, lA0); gload_lds16(gA1, lA1);
    gload_lds16(gB0, lB0); gload_lds16(gB1, lB1);
    gA0 += 32; gA1 += 32; gB0 += 32; gB1 += 32;
    __syncthreads();
    bf16x8 af[4], bf[4];
#pragma unroll
    for (int i = 0; i < 4; ++i) af[i] = *(bf16x8*)&As[(wr + i * 16 + lr) * 32 + g * 8];
#pragma unroll
    for (int j = 0; j < 4; ++j) bf[j] = *(bf16x8*)&Bs[(wc + j * 16 + lr) * 32 + g * 8];
#pragma unroll
    for (int i = 0; i < 4; ++i)
#pragma unroll
      for (int j = 0; j < 4; ++j)
        acc[i][j] = __builtin_amdgcn_mfma_f32_16x16x32_bf16(af[i], bf[j], acc[i][j], 0, 0, 0);
    __syncthreads();
  }

#pragma unroll
  for (int i = 0; i < 4; ++i) {
#pragma unroll
    for (int r = 0; r < 4; ++r) {
      int m = m0 + wr + i * 16 + g * 4 + r;
#pragma unroll
      for (int j = 0; j < 4; ++j) {
        int n = n0 + wc + j * 16 + lr;
        outp[(size_t)m * E_ + n] = acc[i][j][r] + bias[n];
      }
    }
  }
}

extern "C" void kernel_launch(void* const* d_in, const int* in_sizes, int n_in,
                              void* d_out, int out_size, void* d_ws, size_t ws_size,
                              hipStream_t stream) {
  const float* x      = (const float*)d_in[0];
  const float* Wqkv   = (const float*)d_in[1];
  const float* bqkv   = (const float*)d_in[2];
  const float* Wout   = (const float*)d_in[3];
  const float* bout   = (const float*)d_in[4];
  const float* Wimp   = (const float*)d_in[5];
  const float* bimp   = (const float*)d_in[6];
  const float* Walpha = (const float*)d_in[7];
  const float* balpha = (const float*)d_in[8];
  const float* thr    = (const float*)d_in[9];
  const float* log_k  = (const float*)d_in[10];
  const float* qk_sc  = (const float*)d_in[11];
  float* out = (float*)d_out;

  char* ws = (char*)d_ws;
  size_t off = 0;
  auto alloc = [&](size_t bytes) -> void* {
    void* p = (void*)(ws + off);
    off += (bytes + 255) & ~(size_t)255;
    return p;
  };
  const size_t qkv_elems = (size_t)B_ * H_ * T_ * D_;
  __bf16* xb    = (__bf16*)alloc((size_t)M_ * E_ * 2);
  __bf16* Wqkvb = (__bf16*)alloc((size_t)3 * E_ * E_ * 2);
  __bf16* Woutb = (__bf16*)alloc((size_t)E_ * E_ * 2);
  __bf16* q   = (__bf16*)alloc(qkv_elems * 2);
  __bf16* k   = (__bf16*)alloc(qkv_elems * 2);
  __bf16* v   = (__bf16*)alloc(qkv_elems * 2);
  __bf16* qh  = (__bf16*)alloc(qkv_elems * 2);
  __bf16* khn = (__bf16*)alloc(qkv_elems * 2);
  __bf16* yw  = (__bf16*)alloc((size_t)M_ * E_ * 2);
  float* alphaw = (float*)alloc((size_t)B_ * H_ * T_ * sizeof(float));
  float* spikew = (float*)alloc((size_t)M_ * sizeof(float));

  conv_kernel<<<1024, 256, 0, stream>>>(x, Wqkv, Wout, xb, Wqkvb, Woutb);
  imp_alpha_kernel<<<M_, 256, 0, stream>>>(x, Wimp, bimp, Walpha, balpha, thr,
                                           spikew, alphaw);
  qkv_gemm_kernel<<<dim3(24, 16), 256, 0, stream>>>(xb, Wqkvb, bqkv, q, k, v);
  hyp_kernel<<<(2 * B_ * H_ * T_) / 4, 256, 0, stream>>>(q, k, qk_sc, qh, khn);
  attn_kernel<<<B_ * H_ * (T_ / 64), 256, 0, stream>>>(q, k, v, qh, khn,
                                                       alphaw, spikew, log_k, yw);
  out_gemm_kernel<<<dim3(8, 16), 256, 0, stream>>>(yw, Woutb, bout, out);
}

// Round 5
// 157.912 us; speedup vs baseline: 1.0828x; 1.0828x over previous
//
#include <hip/hip_runtime.h>
#include <math.h>

#define B_ 2
#define T_ 1024
#define E_ 1024
#define H_ 16
#define D_ 64
#define M_ (B_*T_)

typedef __bf16 bf16x8 __attribute__((ext_vector_type(8)));
typedef __bf16 bf16x4 __attribute__((ext_vector_type(4)));
typedef float f32x4 __attribute__((ext_vector_type(4)));

// swizzled LDS addressing for attn tiles: row-major [64 rows][128 bytes], byte ^= (row&7)<<4
__device__ __forceinline__ void* ldsp(__bf16* base, int row, int byte) {
  return (char*)base + row * 128 + (byte ^ ((row & 7) << 4));
}

__device__ __forceinline__ void gload_lds16(const void* g, void* l) {
  __builtin_amdgcn_global_load_lds((const __attribute__((address_space(1))) void*)g,
                                   (__attribute__((address_space(3))) void*)l, 16, 0, 0);
}

// ---------------- K-1: f32 -> bf16 conversions (x, Wqkv, Wout) ----------------
#define XV4 524288     // (2*1024*1024)/4
#define WQV4 786432    // (3072*1024)/4
#define WOV4 262144    // (1024*1024)/4
#define TOTV4 (XV4 + WQV4 + WOV4)
__global__ __launch_bounds__(256) void conv_kernel(
    const float* __restrict__ x, const float* __restrict__ Wqkv,
    const float* __restrict__ Wout,
    __bf16* __restrict__ xb, __bf16* __restrict__ Wqkvb, __bf16* __restrict__ Woutb) {
  for (size_t i = (size_t)blockIdx.x * blockDim.x + threadIdx.x; i < TOTV4;
       i += (size_t)gridDim.x * blockDim.x) {
    const float4* src; __bf16* dst; size_t off;
    if (i < XV4)            { src = (const float4*)x;    dst = xb;    off = i; }
    else if (i < XV4+WQV4)  { src = (const float4*)Wqkv; dst = Wqkvb; off = i - XV4; }
    else                    { src = (const float4*)Wout; dst = Woutb; off = i - XV4 - WQV4; }
    float4 val = src[off];
    bf16x4 o = {(__bf16)val.x, (__bf16)val.y, (__bf16)val.z, (__bf16)val.w};
    *(bf16x4*)(dst + off * 4) = o;
  }
}

// ---------------- K0: importance (spike) + alpha (f32 — sign decision!) ----------------
__global__ __launch_bounds__(256) void imp_alpha_kernel(
    const float* __restrict__ x,
    const float* __restrict__ Wimp, const float* __restrict__ bimp,
    const float* __restrict__ Walpha, const float* __restrict__ balpha,
    const float* __restrict__ thr_p,
    float* __restrict__ spike, float* __restrict__ alpha) {
  int m = blockIdx.x;
  int tid = threadIdx.x;
  const float* xr = x + (size_t)m * E_;
  float part[17];
#pragma unroll
  for (int i = 0; i < 17; ++i) part[i] = 0.f;
  for (int e = tid; e < E_; e += 256) {
    float xv = xr[e];
    part[16] += xv * Wimp[e];
#pragma unroll
    for (int h = 0; h < 16; ++h) part[h] += xv * Walpha[h * E_ + e];
  }
  __shared__ float red[17][4];
  int lane = tid & 63, wv = tid >> 6;
#pragma unroll
  for (int i = 0; i < 17; ++i) {
    float v = part[i];
    for (int off = 32; off > 0; off >>= 1) v += __shfl_down(v, off, 64);
    if (lane == 0) red[i][wv] = v;
  }
  __syncthreads();
  if (tid < 17) {
    float v = red[tid][0] + red[tid][1] + red[tid][2] + red[tid][3];
    if (tid == 16) {
      float z = v + bimp[0];
      float sig = 1.f / (1.f + expf(-z));
      spike[m] = (sig > thr_p[0]) ? 1.f : 0.f;
    } else {
      float z = v + balpha[tid];
      float a = 1.f / (1.f + expf(-z));
      int b = m >> 10, t = m & (T_ - 1);
      alpha[((size_t)(b * H_ + tid)) * T_ + t] = a;
    }
  }
}

// ---------------- K1: QKV GEMM — bf16 MFMA, 128x128 tile ----------------
__global__ __launch_bounds__(256) void qkv_gemm_kernel(
    const __bf16* __restrict__ A, const __bf16* __restrict__ Bm,
    const float* __restrict__ bias,
    __bf16* __restrict__ q, __bf16* __restrict__ k, __bf16* __restrict__ v) {
  __shared__ __bf16 As[128 * 32];
  __shared__ __bf16 Bs[128 * 32];
  const int K = E_;
  int tid = threadIdx.x;
  int w = tid >> 6, lane = tid & 63, lr = lane & 15, g = lane >> 4;
  int m0 = blockIdx.y * 128, n0 = blockIdx.x * 128;
  int wr = (w >> 1) * 64, wc = (w & 1) * 64;

  int task0 = tid, task1 = tid + 256;
  int r0s = task0 >> 2, c0s = task0 & 3;
  int r1s = task1 >> 2, c1s = task1 & 3;
  const __bf16* gA0 = A + (size_t)(m0 + r0s) * K + c0s * 8;
  const __bf16* gA1 = A + (size_t)(m0 + r1s) * K + c1s * 8;
  const __bf16* gB0 = Bm + (size_t)(n0 + r0s) * K + c0s * 8;
  const __bf16* gB1 = Bm + (size_t)(n0 + r1s) * K + c1s * 8;
  __bf16* lA0 = As + task0 * 8;
  __bf16* lA1 = As + task1 * 8;
  __bf16* lB0 = Bs + task0 * 8;
  __bf16* lB1 = Bs + task1 * 8;

  f32x4 acc[4][4];
#pragma unroll
  for (int i = 0; i < 4; ++i)
#pragma unroll
    for (int j = 0; j < 4; ++j) acc[i][j] = (f32x4){0.f, 0.f, 0.f, 0.f};

  for (int k0 = 0; k0 < K; k0 += 32) {
    gload_lds16(gA0, lA0); gload_lds16(gA1, lA1);
    gload_lds16(gB0, lB0); gload_lds16(gB1, lB1);
    gA0 += 32; gA1 += 32; gB0 += 32; gB1 += 32;
    __syncthreads();
    bf16x8 af[4], bf[4];
#pragma unroll
    for (int i = 0; i < 4; ++i) af[i] = *(bf16x8*)&As[(wr + i * 16 + lr) * 32 + g * 8];
#pragma unroll
    for (int j = 0; j < 4; ++j) bf[j] = *(bf16x8*)&Bs[(wc + j * 16 + lr) * 32 + g * 8];
#pragma unroll
    for (int i = 0; i < 4; ++i)
#pragma unroll
      for (int j = 0; j < 4; ++j)
        acc[i][j] = __builtin_amdgcn_mfma_f32_16x16x32_bf16(af[i], bf[j], acc[i][j], 0, 0, 0);
    __syncthreads();
  }

#pragma unroll
  for (int i = 0; i < 4; ++i) {
#pragma unroll
    for (int r = 0; r < 4; ++r) {
      int m = m0 + wr + i * 16 + g * 4 + r;
      int b = m >> 10, t = m & (T_ - 1);
#pragma unroll
      for (int j = 0; j < 4; ++j) {
        int n = n0 + wc + j * 16 + lr;
        float val = acc[i][j][r] + bias[n];
        int comp = n >> 10, h = (n >> 6) & 15, d = n & 63;
        __bf16* dst = (comp == 0) ? q : ((comp == 1) ? k : v);
        dst[(((size_t)(b * H_ + h)) * T_ + t) * 64 + d] = (__bf16)val;
      }
    }
  }
}

// ---------------- K2: hyperboloid map (bf16 in/out, f32 math) ----------------
__global__ __launch_bounds__(256) void hyp_kernel(
    const __bf16* __restrict__ q, const __bf16* __restrict__ k,
    const float* __restrict__ qk_scale_p,
    __bf16* __restrict__ qh, __bf16* __restrict__ khn) {
  int wid = blockIdx.x * 4 + (threadIdx.x >> 6);
  int lane = threadIdx.x & 63;
  int is_k = wid >> 15;
  int row = wid & 32767;
  const __bf16* src = (is_k ? k : q) + (size_t)row * 64;
  float u = (float)src[lane];
  float nsq = u * u;
#pragma unroll
  for (int off = 32; off > 0; off >>= 1) nsq += __shfl_xor(nsq, off, 64);
  float norm = fmaxf(sqrtf(nsq), 1e-12f);
  float ss = 1.5f / (1.f + expf(-qk_scale_p[0]));
  float un = u / norm * ss;
  float s2 = un * un;
  float tot = s2;
#pragma unroll
  for (int off = 32; off > 0; off >>= 1) tot += __shfl_xor(tot, off, 64);
  float un0 = __shfl(un, 0, 64);
  float mink = tot - 2.f * un0 * un0;
  float nomin = sqrtf(fmaxf(mink, 1e-8f));
  float sc = sinhf(nomin) / nomin;
  float r = sc * un;
  float sp2 = (lane == 0) ? 0.f : r * r;
  float sps = sp2;
#pragma unroll
  for (int off = 32; off > 0; off >>= 1) sps += __shfl_xor(sps, off, 64);
  float tm = sqrtf(1.f + sps);
  float outv = (lane == 0) ? tm : r;
  if (is_k && lane != 0) outv = -outv;  // fold Minkowski sign
  (is_k ? khn : qh)[(size_t)row * 64 + lane] = (__bf16)outv;
}

// ---------------- K3: MFMA dual-geometry flash attention ----------------
// balanced pairing: blocks (c, c+256) land on the same CU under both the
// sequential and XCD-round-robin dispatch models; qi mapping makes each
// pair's tile count sum to 17 (vs 24 worst-case for naive ordering).
__global__ __launch_bounds__(256) void attn_kernel(
    const __bf16* __restrict__ q, const __bf16* __restrict__ k, const __bf16* __restrict__ v,
    const __bf16* __restrict__ qh, const __bf16* __restrict__ khn,
    const float* __restrict__ alpha, const float* __restrict__ spike,
    const float* __restrict__ log_k, __bf16* __restrict__ y) {
  __shared__ __bf16 q_s[64 * 64];
  __shared__ __bf16 qh_s[64 * 64];
  __shared__ __bf16 k_s[64 * 64];
  __shared__ __bf16 kh_s[64 * 64];
  __shared__ __bf16 vt_s[64 * 64];
  __shared__ __bf16 p_s[64 * 64];

  int bid = blockIdx.x;
  int bq = bid >> 5;                         // 0..15
  int qi = (bq < 8) ? (15 - bq) : (bq - 8);  // pair work: (16-u)+(u+1)=17
  int bh = bid & 31;
  int b = bh >> 4, h = bh & 15;
  int t0 = qi * 64;
  int tid = threadIdx.x;
  int w = tid >> 6, lane = tid & 63;
  int lr = lane & 15, g = lane >> 4;
  int trow = w * 16;
  const size_t base = (size_t)bh * T_ * 64;

#pragma unroll
  for (int it = 0; it < 2; ++it) {
    int task = tid + it * 256;
    int row = task >> 3, cj = task & 7;
    bf16x8 a = *(const bf16x8*)(q + base + (size_t)(t0 + row) * 64 + cj * 8);
    bf16x8 c = *(const bf16x8*)(qh + base + (size_t)(t0 + row) * 64 + cj * 8);
    *(bf16x8*)ldsp(q_s, row, cj * 16) = a;
    *(bf16x8*)ldsp(qh_s, row, cj * 16) = c;
  }

  // constants (log2-domain softmax: fold log2e into both blend scales)
  float curv = log1pf(expf(log_k[h])) + 1e-6f;
  float hc = 0.69314718056f / curv;        // ln2/curv (dist in log2 units)
  const float ec = 0.18033688f;            // 0.125 * log2(e)
  int tg[4];
  float al[4], spv[4];
#pragma unroll
  for (int r = 0; r < 4; ++r) {
    tg[r] = t0 + trow + g * 4 + r;
    al[r] = alpha[(size_t)bh * T_ + tg[r]];
    spv[r] = spike[(size_t)b * T_ + tg[r]];
  }

  __syncthreads();
  bf16x8 aq0 = *(bf16x8*)ldsp(q_s, trow + lr, g * 16);
  bf16x8 aq1 = *(bf16x8*)ldsp(q_s, trow + lr, 64 + g * 16);
  bf16x8 ah0 = *(bf16x8*)ldsp(qh_s, trow + lr, g * 16);
  bf16x8 ah1 = *(bf16x8*)ldsp(qh_s, trow + lr, 64 + g * 16);

  float m_r[4] = {-1e30f, -1e30f, -1e30f, -1e30f};
  float l_r[4] = {0.f, 0.f, 0.f, 0.f};
  f32x4 acc[4];
#pragma unroll
  for (int n = 0; n < 4; ++n) acc[n] = (f32x4){0.f, 0.f, 0.f, 0.f};

  for (int st = 0; st <= qi; ++st) {
    int s0 = st * 64;
    bool diag = (st == qi);
    __syncthreads();
    // ---- stage K, KH, V^T (in-loop, round-3 style) ----
#pragma unroll
    for (int it = 0; it < 2; ++it) {
      int task = tid + it * 256;
      int row = task >> 3, cj = task & 7;
      bf16x8 a = *(const bf16x8*)(k + base + (size_t)(s0 + row) * 64 + cj * 8);
      bf16x8 c = *(const bf16x8*)(khn + base + (size_t)(s0 + row) * 64 + cj * 8);
      *(bf16x8*)ldsp(k_s, row, cj * 16) = a;
      *(bf16x8*)ldsp(kh_s, row, cj * 16) = c;
    }
#pragma unroll
    for (int it = 0; it < 2; ++it) {
      int task = tid + it * 256;
      int srow = task & 63, dc = task >> 6;
      bf16x8 a = *(const bf16x8*)(v + base + (size_t)(s0 + srow) * 64 + dc * 8);
#pragma unroll
      for (int i = 0; i < 8; ++i)
        *(__bf16*)ldsp(vt_s, dc * 8 + i, srow * 2) = a[i];
    }
    __syncthreads();

    // ---- per-j: MFMA scores + blend (causal only on diagonal tile) ----
    float pv[4][4];
    float pmax[4] = {-1e30f, -1e30f, -1e30f, -1e30f};
#pragma unroll
    for (int j = 0; j < 4; ++j) {
      if (diag && (s0 + j * 16 > t0 + trow + 15)) {   // wave-uniform: fully masked
#pragma unroll
        for (int r = 0; r < 4; ++r) pv[j][r] = -1e30f;
        continue;
      }
      bf16x8 bk0 = *(bf16x8*)ldsp(k_s, j * 16 + lr, g * 16);
      bf16x8 bk1 = *(bf16x8*)ldsp(k_s, j * 16 + lr, 64 + g * 16);
      f32x4 z = {0.f, 0.f, 0.f, 0.f};
      z = __builtin_amdgcn_mfma_f32_16x16x32_bf16(aq0, bk0, z, 0, 0, 0);
      f32x4 se = __builtin_amdgcn_mfma_f32_16x16x32_bf16(aq1, bk1, z, 0, 0, 0);
      bf16x8 bh0 = *(bf16x8*)ldsp(kh_s, j * 16 + lr, g * 16);
      bf16x8 bh1 = *(bf16x8*)ldsp(kh_s, j * 16 + lr, 64 + g * 16);
      f32x4 z2 = {0.f, 0.f, 0.f, 0.f};
      z2 = __builtin_amdgcn_mfma_f32_16x16x32_bf16(ah0, bh0, z2, 0, 0, 0);
      f32x4 sh = __builtin_amdgcn_mfma_f32_16x16x32_bf16(ah1, bh1, z2, 0, 0, 0);
      int sg = s0 + j * 16 + lr;
#pragma unroll
      for (int r = 0; r < 4; ++r) {
        float sc_e = se[r] * ec;
        float md = fmaxf(sh[r], 1.0f + 1e-6f);
        float l2 = __log2f(md + sqrtf(fmaf(md, md, -1.f)));  // acosh, log2 units
        float t = fmaf(l2 * l2, hc, sc_e);
        float s = fmaf(-al[r], t, sc_e);                      // (1-a)e - a*h
        if (diag && sg > tg[r]) s = -1e30f;
        pv[j][r] = s;
        pmax[r] = fmaxf(pmax[r], s);
      }
    }
    // ---- online softmax (log2 domain) ----
#pragma unroll
    for (int r = 0; r < 4; ++r) {
      float mx = pmax[r];
      mx = fmaxf(mx, __shfl_xor(mx, 1, 64));
      mx = fmaxf(mx, __shfl_xor(mx, 2, 64));
      mx = fmaxf(mx, __shfl_xor(mx, 4, 64));
      mx = fmaxf(mx, __shfl_xor(mx, 8, 64));
      float mn = fmaxf(m_r[r], mx);
      float fac = exp2f(m_r[r] - mn);
      m_r[r] = mn;
      float ls = 0.f;
#pragma unroll
      for (int j = 0; j < 4; ++j) { pv[j][r] = exp2f(pv[j][r] - mn); ls += pv[j][r]; }
      ls += __shfl_xor(ls, 1, 64);
      ls += __shfl_xor(ls, 2, 64);
      ls += __shfl_xor(ls, 4, 64);
      ls += __shfl_xor(ls, 8, 64);
      l_r[r] = l_r[r] * fac + ls;
#pragma unroll
      for (int n = 0; n < 4; ++n) acc[n][r] *= fac;
    }
#pragma unroll
    for (int j = 0; j < 4; ++j)
#pragma unroll
      for (int r = 0; r < 4; ++r)
        *(__bf16*)ldsp(p_s, trow + g * 4 + r, (j * 16 + lr) * 2) = (__bf16)pv[j][r];
    __syncthreads();

    bf16x8 ap0 = *(bf16x8*)ldsp(p_s, trow + lr, g * 16);
    bf16x8 ap1 = *(bf16x8*)ldsp(p_s, trow + lr, 64 + g * 16);
#pragma unroll
    for (int n = 0; n < 4; ++n) {
      bf16x8 bv0 = *(bf16x8*)ldsp(vt_s, n * 16 + lr, g * 16);
      bf16x8 bv1 = *(bf16x8*)ldsp(vt_s, n * 16 + lr, 64 + g * 16);
      acc[n] = __builtin_amdgcn_mfma_f32_16x16x32_bf16(ap0, bv0, acc[n], 0, 0, 0);
      acc[n] = __builtin_amdgcn_mfma_f32_16x16x32_bf16(ap1, bv1, acc[n], 0, 0, 0);
    }
  }

#pragma unroll
  for (int r = 0; r < 4; ++r) {
    float iv = spv[r] / l_r[r];
#pragma unroll
    for (int n = 0; n < 4; ++n) {
      y[((size_t)(b * T_ + tg[r])) * E_ + h * 64 + n * 16 + lr] =
          (__bf16)(acc[n][r] * iv);
    }
  }
}

// ---------------- K4: output projection — bf16 MFMA, f32 out ----------------
__global__ __launch_bounds__(256) void out_gemm_kernel(
    const __bf16* __restrict__ A, const __bf16* __restrict__ Bm,
    const float* __restrict__ bias, float* __restrict__ outp) {
  __shared__ __bf16 As[128 * 32];
  __shared__ __bf16 Bs[128 * 32];
  const int K = E_;
  int tid = threadIdx.x;
  int w = tid >> 6, lane = tid & 63, lr = lane & 15, g = lane >> 4;
  int m0 = blockIdx.y * 128, n0 = blockIdx.x * 128;
  int wr = (w >> 1) * 64, wc = (w & 1) * 64;

  int task0 = tid, task1 = tid + 256;
  int r0s = task0 >> 2, c0s = task0 & 3;
  int r1s = task1 >> 2, c1s = task1 & 3;
  const __bf16* gA0 = A + (size_t)(m0 + r0s) * K + c0s * 8;
  const __bf16* gA1 = A + (size_t)(m0 + r1s) * K + c1s * 8;
  const __bf16* gB0 = Bm + (size_t)(n0 + r0s) * K + c0s * 8;
  const __bf16* gB1 = Bm + (size_t)(n0 + r1s) * K + c1s * 8;
  __bf16* lA0 = As + task0 * 8;
  __bf16* lA1 = As + task1 * 8;
  __bf16* lB0 = Bs + task0 * 8;
  __bf16* lB1 = Bs + task1 * 8;

  f32x4 acc[4][4];
#pragma unroll
  for (int i = 0; i < 4; ++i)
#pragma unroll
    for (int j = 0; j < 4; ++j) acc[i][j] = (f32x4){0.f, 0.f, 0.f, 0.f};

  for (int k0 = 0; k0 < K; k0 += 32) {
    gload_lds16(gA0, lA0); gload_lds16(gA1, lA1);
    gload_lds16(gB0, lB0); gload_lds16(gB1, lB1);
    gA0 += 32; gA1 += 32; gB0 += 32; gB1 += 32;
    __syncthreads();
    bf16x8 af[4], bf[4];
#pragma unroll
    for (int i = 0; i < 4; ++i) af[i] = *(bf16x8*)&As[(wr + i * 16 + lr) * 32 + g * 8];
#pragma unroll
    for (int j = 0; j < 4; ++j) bf[j] = *(bf16x8*)&Bs[(wc + j * 16 + lr) * 32 + g * 8];
#pragma unroll
    for (int i = 0; i < 4; ++i)
#pragma unroll
      for (int j = 0; j < 4; ++j)
        acc[i][j] = __builtin_amdgcn_mfma_f32_16x16x32_bf16(af[i], bf[j], acc[i][j], 0, 0, 0);
    __syncthreads();
  }

#pragma unroll
  for (int i = 0; i < 4; ++i) {
#pragma unroll
    for (int r = 0; r < 4; ++r) {
      int m = m0 + wr + i * 16 + g * 4 + r;
#pragma unroll
      for (int j = 0; j < 4; ++j) {
        int n = n0 + wc + j * 16 + lr;
        outp[(size_t)m * E_ + n] = acc[i][j][r] + bias[n];
      }
    }
  }
}

extern "C" void kernel_launch(void* const* d_in, const int* in_sizes, int n_in,
                              void* d_out, int out_size, void* d_ws, size_t ws_size,
                              hipStream_t stream) {
  const float* x      = (const float*)d_in[0];
  const float* Wqkv   = (const float*)d_in[1];
  const float* bqkv   = (const float*)d_in[2];
  const float* Wout   = (const float*)d_in[3];
  const float* bout   = (const float*)d_in[4];
  const float* Wimp   = (const float*)d_in[5];
  const float* bimp   = (const float*)d_in[6];
  const float* Walpha = (const float*)d_in[7];
  const float* balpha = (const float*)d_in[8];
  const float* thr    = (const float*)d_in[9];
  const float* log_k  = (const float*)d_in[10];
  const float* qk_sc  = (const float*)d_in[11];
  float* out = (float*)d_out;

  char* ws = (char*)d_ws;
  size_t off = 0;
  auto alloc = [&](size_t bytes) -> void* {
    void* p = (void*)(ws + off);
    off += (bytes + 255) & ~(size_t)255;
    return p;
  };
  const size_t qkv_elems = (size_t)B_ * H_ * T_ * D_;
  __bf16* xb    = (__bf16*)alloc((size_t)M_ * E_ * 2);
  __bf16* Wqkvb = (__bf16*)alloc((size_t)3 * E_ * E_ * 2);
  __bf16* Woutb = (__bf16*)alloc((size_t)E_ * E_ * 2);
  __bf16* q   = (__bf16*)alloc(qkv_elems * 2);
  __bf16* k   = (__bf16*)alloc(qkv_elems * 2);
  __bf16* v   = (__bf16*)alloc(qkv_elems * 2);
  __bf16* qh  = (__bf16*)alloc(qkv_elems * 2);
  __bf16* khn = (__bf16*)alloc(qkv_elems * 2);
  __bf16* yw  = (__bf16*)alloc((size_t)M_ * E_ * 2);
  float* alphaw = (float*)alloc((size_t)B_ * H_ * T_ * sizeof(float));
  float* spikew = (float*)alloc((size_t)M_ * sizeof(float));

  conv_kernel<<<1024, 256, 0, stream>>>(x, Wqkv, Wout, xb, Wqkvb, Woutb);
  imp_alpha_kernel<<<M_, 256, 0, stream>>>(x, Wimp, bimp, Walpha, balpha, thr,
                                           spikew, alphaw);
  qkv_gemm_kernel<<<dim3(24, 16), 256, 0, stream>>>(xb, Wqkvb, bqkv, q, k, v);
  hyp_kernel<<<(2 * B_ * H_ * T_) / 4, 256, 0, stream>>>(q, k, qk_sc, qh, khn);
  attn_kernel<<<B_ * H_ * (T_ / 64), 256, 0, stream>>>(q, k, v, qh, khn,
                                                       alphaw, spikew, log_k, yw);
  out_gemm_kernel<<<dim3(8, 16), 256, 0, stream>>>(yw, Woutb, bout, out);
}